// Round 1
// baseline (1177.971 us; speedup 1.0000x reference)
//
#include <hip/hip_runtime.h>

#define NN 4096
#define NE 32768
#define PED 16
#define HID 128

// ---- CSR build (one-time, tiny) ----

__global__ void count_kernel(const int* __restrict__ senders,
                             const int* __restrict__ receivers,
                             int* __restrict__ outdeg, int* __restrict__ indeg) {
  int e = blockIdx.x * blockDim.x + threadIdx.x;
  if (e < NE) {
    atomicAdd(&outdeg[senders[e]], 1);
    atomicAdd(&indeg[receivers[e]], 1);
  }
}

__global__ void deg_inv_kernel(const int* __restrict__ outdeg, float* __restrict__ dinv) {
  int i = blockIdx.x * blockDim.x + threadIdx.x;
  if (i < NN) {
    int d = outdeg[i];
    if (d < 1) d = 1;
    dinv[i] = 1.0f / (float)d;
  }
}

// single-block scan of 4096 in-degrees -> row_ptr[0..4096]
__global__ void scan_kernel(const int* __restrict__ indeg, int* __restrict__ row_ptr) {
  __shared__ int part[1024];
  int t = threadIdx.x;
  int base = t * 4;
  int s0 = indeg[base + 0], s1 = indeg[base + 1], s2 = indeg[base + 2], s3 = indeg[base + 3];
  int sum = s0 + s1 + s2 + s3;
  part[t] = sum;
  __syncthreads();
  for (int off = 1; off < 1024; off <<= 1) {
    int v = (t >= off) ? part[t - off] : 0;
    __syncthreads();
    part[t] += v;
    __syncthreads();
  }
  int excl = part[t] - sum;  // exclusive prefix for this thread's 4-chunk
  row_ptr[base + 0] = excl;
  row_ptr[base + 1] = excl + s0;
  row_ptr[base + 2] = excl + s0 + s1;
  row_ptr[base + 3] = excl + s0 + s1 + s2;
  if (t == 1023) row_ptr[NN] = part[1023];
}

__global__ void fill_kernel(const int* __restrict__ senders,
                            const int* __restrict__ receivers,
                            const int* __restrict__ row_ptr,
                            int* __restrict__ fillc,
                            int* __restrict__ cols, float* __restrict__ wgt,
                            const float* __restrict__ dinv) {
  int e = blockIdx.x * blockDim.x + threadIdx.x;
  if (e < NE) {
    int r = receivers[e], s = senders[e];
    int pos = atomicAdd(&fillc[r], 1);
    int slot = row_ptr[r] + pos;
    cols[slot] = s;
    wgt[slot] = dinv[s];
  }
}

// ---- iteration ----

// X0[row*B + col] = (row == c0+col) ? 1 : 0   (grid covers NN*B exactly)
__global__ void init_kernel(float* __restrict__ X0, int c0, int logB) {
  int idx = blockIdx.x * blockDim.x + threadIdx.x;
  int B = 1 << logB;
  int row = idx >> logB;
  int col = idx & (B - 1);
  X0[idx] = (row == c0 + col) ? 1.0f : 0.0f;
}

// one block per (row, column-chunk); gather sender rows via CSR, no atomics
__global__ void step_kernel(const float* __restrict__ X0, float* __restrict__ X1,
                            const int* __restrict__ row_ptr,
                            const int* __restrict__ cols,
                            const float* __restrict__ wgt,
                            float* __restrict__ pe,
                            int B, int chunks, int c0, int k) {
  int bid = blockIdx.x;
  int r = bid / chunks;
  int chunk = bid - r * chunks;
  int col0 = chunk * (blockDim.x << 2) + (threadIdx.x << 2);
  int beg = row_ptr[r], end = row_ptr[r + 1];
  float ax = 0.f, ay = 0.f, az = 0.f, aw = 0.f;
  for (int e = beg; e < end; ++e) {
    int s = cols[e];
    float w = wgt[e];
    const float4 v = *reinterpret_cast<const float4*>(X0 + (size_t)s * B + col0);
    ax = fmaf(w, v.x, ax);
    ay = fmaf(w, v.y, ay);
    az = fmaf(w, v.z, az);
    aw = fmaf(w, v.w, aw);
  }
  float4 o;
  o.x = ax; o.y = ay; o.z = az; o.w = aw;
  *reinterpret_cast<float4*>(X1 + (size_t)r * B + col0) = o;
  // diagonal: row r corresponds to local column r - c0 in this batch
  int dj = r - c0;
  if (dj >= col0 && dj < col0 + 4) {
    int q = dj & 3;
    float dv = q == 0 ? ax : q == 1 ? ay : q == 2 ? az : aw;
    pe[r * PED + k] = dv;
  }
}

// out[r,h] = sum_k pe[r,k] * W[k,h] + b[h]
__global__ void out_kernel(const float* __restrict__ pe, const float* __restrict__ W,
                           const float* __restrict__ bvec, float* __restrict__ out) {
  __shared__ float sW[PED * HID];
  int r = blockIdx.x;
  int h = threadIdx.x;
  for (int i = h; i < PED * HID; i += HID) sW[i] = W[i];
  __syncthreads();
  float acc = bvec[h];
  float p[PED];
#pragma unroll
  for (int kk = 0; kk < PED; ++kk) p[kk] = pe[r * PED + kk];
#pragma unroll
  for (int kk = 0; kk < PED; ++kk) acc = fmaf(p[kk], sW[kk * HID + h], acc);
  out[r * HID + h] = acc;
}

extern "C" void kernel_launch(void* const* d_in, const int* in_sizes, int n_in,
                              void* d_out, int out_size, void* d_ws, size_t ws_size,
                              hipStream_t stream) {
  // inputs: 0=nodes (unused), 1=senders, 2=receivers, 3=W, 4=b
  const int* senders = (const int*)d_in[1];
  const int* receivers = (const int*)d_in[2];
  const float* W = (const float*)d_in[3];
  const float* bvec = (const float*)d_in[4];
  float* out = (float*)d_out;

  char* p = (char*)d_ws;
  int* outdeg = (int*)p;  p += (size_t)NN * 4;
  int* indeg = (int*)p;   p += (size_t)NN * 4;
  int* fillc = (int*)p;   p += (size_t)NN * 4;
  int* row_ptr = (int*)p; p += (size_t)(NN + 4) * 4;
  float* dinv = (float*)p; p += (size_t)NN * 4;
  int* cols = (int*)p;    p += (size_t)NE * 4;
  float* wgt = (float*)p; p += (size_t)NE * 4;
  float* pe = (float*)p;  p += (size_t)NN * PED * 4;
  float* X = (float*)p;
  size_t fixed = (size_t)(p - (char*)d_ws);
  size_t avail = ws_size > fixed ? ws_size - fixed : 0;

  // largest power-of-two column batch that fits: 2 * NN * B * 4 bytes
  int logB = 12;
  while (logB > 6 && (2ull * NN * (1ull << logB) * 4ull) > avail) --logB;
  int B = 1 << logB;

  // zero outdeg/indeg/fillc (contiguous at ws start)
  hipMemsetAsync(d_ws, 0, (size_t)NN * 4 * 3, stream);
  count_kernel<<<NE / 256, 256, 0, stream>>>(senders, receivers, outdeg, indeg);
  deg_inv_kernel<<<NN / 256, 256, 0, stream>>>(outdeg, dinv);
  scan_kernel<<<1, 1024, 0, stream>>>(indeg, row_ptr);
  fill_kernel<<<NE / 256, 256, 0, stream>>>(senders, receivers, row_ptr, fillc, cols, wgt, dinv);

  int cols_per_block = B < 1024 ? B : 1024;
  int threads = cols_per_block / 4;
  int chunks = B / cols_per_block;
  float* X0 = X;
  float* X1 = X + (size_t)NN * B;

  for (int c0 = 0; c0 < NN; c0 += B) {
    init_kernel<<<(NN * B) / 256, 256, 0, stream>>>(X0, c0, logB);
    float* a = X0;
    float* b = X1;
    for (int k = 0; k < PED; ++k) {
      step_kernel<<<NN * chunks, threads, 0, stream>>>(a, b, row_ptr, cols, wgt, pe, B, chunks, c0, k);
      float* t = a; a = b; b = t;
    }
  }

  out_kernel<<<NN, HID, 0, stream>>>(pe, W, bvec, out);
}

// Round 2
// 891.022 us; speedup vs baseline: 1.3220x; 1.3220x over previous
//
#include <hip/hip_runtime.h>

#define NN 4096
#define NE 32768
#define PED 16
#define HID 128

typedef _Float16 h_t;
typedef _Float16 h4 __attribute__((ext_vector_type(4)));
typedef _Float16 h8 __attribute__((ext_vector_type(8)));

// ---- CSR build (one-time, tiny) ----

__global__ void count_kernel(const int* __restrict__ senders,
                             const int* __restrict__ receivers,
                             int* __restrict__ outdeg, int* __restrict__ indeg) {
  int e = blockIdx.x * blockDim.x + threadIdx.x;
  if (e < NE) {
    atomicAdd(&outdeg[senders[e]], 1);
    atomicAdd(&indeg[receivers[e]], 1);
  }
}

__global__ void deg_inv_kernel(const int* __restrict__ outdeg, float* __restrict__ dinv) {
  int i = blockIdx.x * blockDim.x + threadIdx.x;
  if (i < NN) {
    int d = outdeg[i];
    if (d < 1) d = 1;
    dinv[i] = 1.0f / (float)d;
  }
}

// single-block scan of 4096 in-degrees -> row_ptr[0..4096]
__global__ void scan_kernel(const int* __restrict__ indeg, int* __restrict__ row_ptr) {
  __shared__ int part[1024];
  int t = threadIdx.x;
  int base = t * 4;
  int s0 = indeg[base + 0], s1 = indeg[base + 1], s2 = indeg[base + 2], s3 = indeg[base + 3];
  int sum = s0 + s1 + s2 + s3;
  part[t] = sum;
  __syncthreads();
  for (int off = 1; off < 1024; off <<= 1) {
    int v = (t >= off) ? part[t - off] : 0;
    __syncthreads();
    part[t] += v;
    __syncthreads();
  }
  int excl = part[t] - sum;
  row_ptr[base + 0] = excl;
  row_ptr[base + 1] = excl + s0;
  row_ptr[base + 2] = excl + s0 + s1;
  row_ptr[base + 3] = excl + s0 + s1 + s2;
  if (t == 1023) row_ptr[NN] = part[1023];
}

__global__ void fill_kernel(const int* __restrict__ senders,
                            const int* __restrict__ receivers,
                            const int* __restrict__ row_ptr,
                            int* __restrict__ fillc,
                            int* __restrict__ cols, float* __restrict__ wgt,
                            const float* __restrict__ dinv) {
  int e = blockIdx.x * blockDim.x + threadIdx.x;
  if (e < NE) {
    int r = receivers[e], s = senders[e];
    int pos = atomicAdd(&fillc[r], 1);
    int slot = row_ptr[r] + pos;
    cols[slot] = s;
    wgt[slot] = dinv[s];
  }
}

// ---- iteration ----

// identity (fp16), 8 cols per thread
__global__ void init_h(h_t* __restrict__ X0, int c0, int logB) {
  int idx = blockIdx.x * blockDim.x + threadIdx.x;
  int row = idx >> (logB - 3);
  int col8 = (idx - (row << (logB - 3))) << 3;
  int dj = row - c0;
  h8 v;
#pragma unroll
  for (int j = 0; j < 8; ++j) v[j] = (h_t)((dj == col8 + j) ? 1.0f : 0.0f);
  *reinterpret_cast<h8*>(X0 + ((size_t)row << logB) + col8) = v;
}

// block = 256 threads = 4 waves; each wave owns one row and a 256-column chunk.
// swz: chunk = bid%8 (+8 for second half) so each XCD's L2 holds its own
// 2 MB X0-slice + 2 MB X1-slice (fits 4 MB exactly).
__global__ void step_kernel(const h_t* __restrict__ X0, h_t* __restrict__ X1,
                            const int* __restrict__ row_ptr,
                            const int* __restrict__ cols,
                            const float* __restrict__ wgt,
                            float* __restrict__ pe,
                            int logB, int chunks, int c0, int k, int swz) {
  int bid = blockIdx.x;
  int rg, chunk;
  if (swz) {
    int x = bid & 7;
    int slot = bid >> 3;
    chunk = x + ((slot >> 10) << 3);  // nrg = NN/4 = 1024
    rg = slot & 1023;
  } else {
    chunk = bid % chunks;
    rg = bid / chunks;
  }
  int wave = threadIdx.x >> 6;
  int lane = threadIdx.x & 63;
  int r = (rg << 2) + wave;
  int col0 = (chunk << 8) + (lane << 2);  // 4 halves per lane
  int beg = row_ptr[r], end = row_ptr[r + 1];
  float a0 = 0.f, a1 = 0.f, a2 = 0.f, a3 = 0.f;
  for (int e = beg; e < end; ++e) {
    int s = cols[e];
    float w = wgt[e];
    h4 v = *reinterpret_cast<const h4*>(X0 + ((size_t)s << logB) + col0);
    a0 = fmaf(w, (float)v.x, a0);
    a1 = fmaf(w, (float)v.y, a1);
    a2 = fmaf(w, (float)v.z, a2);
    a3 = fmaf(w, (float)v.w, a3);
  }
  h4 o;
  o.x = (h_t)a0; o.y = (h_t)a1; o.z = (h_t)a2; o.w = (h_t)a3;
  *reinterpret_cast<h4*>(X1 + ((size_t)r << logB) + col0) = o;
  // diagonal from the fp32 accumulator (pre-rounding)
  int dj = r - c0;
  if (dj >= col0 && dj < col0 + 4) {
    int q = dj & 3;
    float dv = q == 0 ? a0 : q == 1 ? a1 : q == 2 ? a2 : a3;
    pe[r * PED + k] = dv;
  }
}

// out[r,h] = sum_k pe[r,k] * W[k,h] + b[h]
__global__ void out_kernel(const float* __restrict__ pe, const float* __restrict__ W,
                           const float* __restrict__ bvec, float* __restrict__ out) {
  __shared__ float sW[PED * HID];
  int r = blockIdx.x;
  int h = threadIdx.x;
  for (int i = h; i < PED * HID; i += HID) sW[i] = W[i];
  __syncthreads();
  float acc = bvec[h];
  float p[PED];
#pragma unroll
  for (int kk = 0; kk < PED; ++kk) p[kk] = pe[r * PED + kk];
#pragma unroll
  for (int kk = 0; kk < PED; ++kk) acc = fmaf(p[kk], sW[kk * HID + h], acc);
  out[r * HID + h] = acc;
}

extern "C" void kernel_launch(void* const* d_in, const int* in_sizes, int n_in,
                              void* d_out, int out_size, void* d_ws, size_t ws_size,
                              hipStream_t stream) {
  // inputs: 0=nodes (unused), 1=senders, 2=receivers, 3=W, 4=b
  const int* senders = (const int*)d_in[1];
  const int* receivers = (const int*)d_in[2];
  const float* W = (const float*)d_in[3];
  const float* bvec = (const float*)d_in[4];
  float* out = (float*)d_out;

  char* p = (char*)d_ws;
  int* outdeg = (int*)p;  p += (size_t)NN * 4;
  int* indeg = (int*)p;   p += (size_t)NN * 4;
  int* fillc = (int*)p;   p += (size_t)NN * 4;
  int* row_ptr = (int*)p; p += (size_t)(NN + 4) * 4;
  float* dinv = (float*)p; p += (size_t)NN * 4;
  int* cols = (int*)p;    p += (size_t)NE * 4;
  float* wgt = (float*)p; p += (size_t)NE * 4;
  float* pe = (float*)p;  p += (size_t)NN * PED * 4;
  h_t* X = (h_t*)p;
  size_t fixed = (size_t)(p - (char*)d_ws);
  size_t avail = ws_size > fixed ? ws_size - fixed : 0;

  // largest power-of-two column batch that fits: 2 * NN * B * 2 bytes (fp16)
  int logB = 12;
  while (logB > 8 && (2ull * NN * (1ull << logB) * 2ull) > avail) --logB;
  int B = 1 << logB;
  int chunks = B >> 8;           // 256 columns per chunk
  int swz = (chunks == 16) ? 1 : 0;
  int nblk = (NN / 4) * chunks;  // 4 rows per block (one per wave)

  hipMemsetAsync(d_ws, 0, (size_t)NN * 4 * 3, stream);
  count_kernel<<<NE / 256, 256, 0, stream>>>(senders, receivers, outdeg, indeg);
  deg_inv_kernel<<<NN / 256, 256, 0, stream>>>(outdeg, dinv);
  scan_kernel<<<1, 1024, 0, stream>>>(indeg, row_ptr);
  fill_kernel<<<NE / 256, 256, 0, stream>>>(senders, receivers, row_ptr, fillc, cols, wgt, dinv);

  h_t* X0 = X;
  h_t* X1 = X + (size_t)NN * B;

  for (int c0 = 0; c0 < NN; c0 += B) {
    init_h<<<(NN * B / 8) / 256, 256, 0, stream>>>(X0, c0, logB);
    h_t* a = X0;
    h_t* b = X1;
    for (int k = 0; k < PED; ++k) {
      step_kernel<<<nblk, 256, 0, stream>>>(a, b, row_ptr, cols, wgt, pe, logB, chunks, c0, k, swz);
      h_t* t = a; a = b; b = t;
    }
  }

  out_kernel<<<NN, HID, 0, stream>>>(pe, W, bvec, out);
}

// Round 3
// 331.862 us; speedup vs baseline: 3.5496x; 2.6849x over previous
//
#include <hip/hip_runtime.h>

#define NN 4096
#define NE 32768
#define PED 16
#define HID 128
#define CW 16          // columns per block slice
#define NCHUNK 64      // NN / 64 rows per chunk
#define THREADS 512

typedef _Float16 h_t;
typedef _Float16 h8 __attribute__((ext_vector_type(8)));

// swizzled LDS index (ushort units) for row s, half (0: cols 0-7, 1: cols 8-15).
// 128-B window of 4 rows; granule slot g depends on s%8 -> random-row gathers
// spread across all 32 banks. xidx(s,1) == xidx(s,0) ^ 8.
__device__ __forceinline__ int xidx(int s, int half) {
  int g = ((s & 3) << 1) | (half ^ ((s >> 2) & 1));
  return ((s >> 2) << 6) + (g << 3);
}

// ---- preprocessing (tiny, one-time) ----

__global__ void count_kernel(const int* __restrict__ senders,
                             const int* __restrict__ receivers,
                             int* __restrict__ outdeg, int* __restrict__ indeg) {
  int e = blockIdx.x * blockDim.x + threadIdx.x;
  if (e < NE) {
    atomicAdd(&outdeg[senders[e]], 1);
    atomicAdd(&indeg[receivers[e]], 1);
  }
}

__global__ void deg_inv_kernel(const int* __restrict__ outdeg, float* __restrict__ dinv) {
  int i = blockIdx.x * blockDim.x + threadIdx.x;
  if (i < NN) {
    int d = outdeg[i];
    if (d < 1) d = 1;
    dinv[i] = 1.0f / (float)d;
  }
}

// counting-sort rows by (clamped) in-degree; chunk max-degrees and ELL offsets
__global__ void sort_kernel(const int* __restrict__ indeg,
                            int* __restrict__ rowperm, int* __restrict__ sortpos,
                            int* __restrict__ chunk_off, int* __restrict__ chunk_max) {
  __shared__ int hist[64];
  __shared__ int base[64];
  int t = threadIdx.x;  // 256 threads
  if (t < 64) hist[t] = 0;
  __syncthreads();
  for (int r = t; r < NN; r += 256) {
    int d = indeg[r]; if (d > 63) d = 63;
    atomicAdd(&hist[d], 1);
  }
  __syncthreads();
  if (t == 0) {
    int acc = 0;
    for (int i = 0; i < 64; ++i) { base[i] = acc; acc += hist[i]; }
  }
  __syncthreads();
  for (int r = t; r < NN; r += 256) {
    int d = indeg[r]; if (d > 63) d = 63;
    int pos = atomicAdd(&base[d], 1);
    rowperm[pos] = r;
    sortpos[r] = pos;
  }
  __syncthreads();
  if (t < NCHUNK) {
    int m = 0;
    for (int i = 0; i < 64; ++i) {
      int d = indeg[rowperm[(t << 6) + i]];
      if (d > m) m = d;
    }
    chunk_max[t] = m;
  }
  __syncthreads();
  if (t == 0) {
    int acc = 0;
    for (int c = 0; c < NCHUNK; ++c) { chunk_off[c] = acc; acc += chunk_max[c] << 6; }
    chunk_off[NCHUNK] = acc;
  }
}

// scatter edges into lane-major padded ELL: entry = {preswizzled LDS idx of sender, w bits}
__global__ void fill_ell(const int* __restrict__ senders, const int* __restrict__ receivers,
                         const int* __restrict__ sortpos, const int* __restrict__ chunk_off,
                         const float* __restrict__ dinv, int* __restrict__ fillc,
                         int2* __restrict__ ell) {
  int e = blockIdx.x * blockDim.x + threadIdx.x;
  if (e < NE) {
    int r = receivers[e], s = senders[e];
    int p = sortpos[r];
    int tslot = atomicAdd(&fillc[r], 1);
    int slot = chunk_off[p >> 6] + (tslot << 6) + (p & 63);
    ell[slot] = make_int2(xidx(s, 0), __float_as_int(dinv[s]));
  }
}

// ---- fused 16-step iteration: block owns cols [c0, c0+16) in LDS for all steps ----

__global__ __launch_bounds__(THREADS, 2)
void fused_kernel(const int2* __restrict__ ell,
                  const int* __restrict__ chunk_off,
                  const int* __restrict__ chunk_max,
                  const int* __restrict__ rowperm,
                  float* __restrict__ pe) {
  __shared__ h_t X[NN * CW];  // 128 KiB, swizzled
  int c0 = blockIdx.x * CW;
  int tid = threadIdx.x;
  int wave = tid >> 6, lane = tid & 63;

  // identity slice init
  for (int s = tid; s < NN; s += THREADS) {
    int d = s - c0;
    h8 lo, hi;
#pragma unroll
    for (int j = 0; j < 8; ++j) {
      lo[j] = (h_t)((d == j) ? 1.0f : 0.0f);
      hi[j] = (h_t)((d == 8 + j) ? 1.0f : 0.0f);
    }
    *reinterpret_cast<h8*>(&X[xidx(s, 0)]) = lo;
    *reinterpret_cast<h8*>(&X[xidx(s, 1)]) = hi;
  }
  __syncthreads();

  for (int k = 0; k < PED; ++k) {
    h8 rlo[8], rhi[8];
    int rr[8];
#pragma unroll
    for (int pass = 0; pass < 8; ++pass) {
      int chunk = (pass << 3) + wave;       // interleaved -> balanced degree sums
      int base = chunk_off[chunk];
      int maxd = chunk_max[chunk];
      int r = rowperm[(chunk << 6) + lane];
      rr[pass] = r;
      float a[16];
#pragma unroll
      for (int j = 0; j < 16; ++j) a[j] = 0.f;
      const int2* ep = ell + base + lane;
      int2 cw = ep[0];                      // safe: cap has +64 slack, padding w=0
      for (int t = 0; t < maxd; ++t) {
        int2 nx = ep[(t + 1) << 6];         // prefetch next coalesced 512B slab
        int idx0 = cw.x;
        float w = __int_as_float(cw.y);
        h8 lo = *reinterpret_cast<const h8*>(&X[idx0]);
        h8 hi = *reinterpret_cast<const h8*>(&X[idx0 ^ 8]);
#pragma unroll
        for (int j = 0; j < 8; ++j) {
          a[j]     = fmaf(w, (float)lo[j], a[j]);
          a[8 + j] = fmaf(w, (float)hi[j], a[8 + j]);
        }
        cw = nx;
      }
      h8 plo, phi;
#pragma unroll
      for (int j = 0; j < 8; ++j) { plo[j] = (h_t)a[j]; phi[j] = (h_t)a[8 + j]; }
      rlo[pass] = plo; rhi[pass] = phi;
      int dj = r - c0;
      if (dj >= 0 && dj < CW) {             // diagonal entry (fp32, pre-rounding)
        float dv = 0.f;
#pragma unroll
        for (int j = 0; j < 16; ++j) dv = (dj == j) ? a[j] : dv;
        pe[r * PED + k] = dv;
      }
    }
    __syncthreads();
#pragma unroll
    for (int pass = 0; pass < 8; ++pass) {
      int r = rr[pass];
      *reinterpret_cast<h8*>(&X[xidx(r, 0)]) = rlo[pass];
      *reinterpret_cast<h8*>(&X[xidx(r, 1)]) = rhi[pass];
    }
    __syncthreads();
  }
}

// out[r,h] = sum_k pe[r,k] * W[k,h] + b[h]
__global__ void out_kernel(const float* __restrict__ pe, const float* __restrict__ W,
                           const float* __restrict__ bvec, float* __restrict__ out) {
  __shared__ float sW[PED * HID];
  int r = blockIdx.x;
  int h = threadIdx.x;
  for (int i = h; i < PED * HID; i += HID) sW[i] = W[i];
  __syncthreads();
  float acc = bvec[h];
  float p[PED];
#pragma unroll
  for (int kk = 0; kk < PED; ++kk) p[kk] = pe[r * PED + kk];
#pragma unroll
  for (int kk = 0; kk < PED; ++kk) acc = fmaf(p[kk], sW[kk * HID + h], acc);
  out[r * HID + h] = acc;
}

extern "C" void kernel_launch(void* const* d_in, const int* in_sizes, int n_in,
                              void* d_out, int out_size, void* d_ws, size_t ws_size,
                              hipStream_t stream) {
  // inputs: 0=nodes (unused), 1=senders, 2=receivers, 3=W, 4=b
  const int* senders = (const int*)d_in[1];
  const int* receivers = (const int*)d_in[2];
  const float* W = (const float*)d_in[3];
  const float* bvec = (const float*)d_in[4];
  float* out = (float*)d_out;

  char* p = (char*)d_ws;
  int* outdeg = (int*)p;    p += (size_t)NN * 4;
  int* indeg = (int*)p;     p += (size_t)NN * 4;
  int* fillc = (int*)p;     p += (size_t)NN * 4;
  float* dinv = (float*)p;  p += (size_t)NN * 4;
  int* rowperm = (int*)p;   p += (size_t)NN * 4;
  int* sortpos = (int*)p;   p += (size_t)NN * 4;
  int* chunk_off = (int*)p; p += 128 * 4;
  int* chunk_max = (int*)p; p += 128 * 4;
  float* pe = (float*)p;    p += (size_t)NN * PED * 4;
  int2* ell = (int2*)p;
  size_t ell_slots = (size_t)64 * NE + 64;  // worst-case padded bound + prefetch slack
  size_t ell_bytes = ell_slots * sizeof(int2);

  // zero outdeg/indeg/fillc (contiguous at ws start) and ELL (padding = col 0, w 0)
  hipMemsetAsync(d_ws, 0, (size_t)NN * 4 * 3, stream);
  hipMemsetAsync(ell, 0, ell_bytes, stream);

  count_kernel<<<NE / 256, 256, 0, stream>>>(senders, receivers, outdeg, indeg);
  deg_inv_kernel<<<NN / 256, 256, 0, stream>>>(outdeg, dinv);
  sort_kernel<<<1, 256, 0, stream>>>(indeg, rowperm, sortpos, chunk_off, chunk_max);
  fill_ell<<<NE / 256, 256, 0, stream>>>(senders, receivers, sortpos, chunk_off, dinv, fillc, ell);

  fused_kernel<<<NN / CW, THREADS, 0, stream>>>(ell, chunk_off, chunk_max, rowperm, pe);

  out_kernel<<<NN, HID, 0, stream>>>(pe, W, bvec, out);
}

// Round 4
// 214.570 us; speedup vs baseline: 5.4899x; 1.5466x over previous
//
#include <hip/hip_runtime.h>

#define NN 4096
#define NE 32768
#define PED 16
#define HID 128
#define CW 16          // columns per block slice
#define NCHUNK 64      // NN/64 rows per chunk
#define THREADS 1024   // 16 waves
#define PASSES 4       // NCHUNK / 16 waves

typedef _Float16 h_t;
typedef _Float16 h8 __attribute__((ext_vector_type(8)));

// swizzled LDS BYTE offset of row s's low half (cols 0-7); high half = ^16.
// 128-B window of 4 rows; granule position g = f(s) spreads random rows
// across all 8 granule slots (hence all 32 banks).
__device__ __forceinline__ int xbyte(int s) {
  int g = ((s & 3) << 1) | ((s >> 2) & 1);
  return ((s >> 2) << 7) + (g << 4);
}

// ---- preprocessing (tiny, one-time) ----

__global__ void count_kernel(const int* __restrict__ senders,
                             const int* __restrict__ receivers,
                             int* __restrict__ outdeg, int* __restrict__ indeg) {
  int e = blockIdx.x * blockDim.x + threadIdx.x;
  if (e < NE) {
    atomicAdd(&outdeg[senders[e]], 1);
    atomicAdd(&indeg[receivers[e]], 1);
  }
}

__global__ void deg_inv_kernel(const int* __restrict__ outdeg, float* __restrict__ dinv) {
  int i = blockIdx.x * blockDim.x + threadIdx.x;
  if (i < NN) {
    int d = outdeg[i];
    if (d < 1) d = 1;
    dinv[i] = 1.0f / (float)d;
  }
}

// counting-sort rows by (clamped) in-degree; chunk max-degrees and ELL offsets
__global__ void sort_kernel(const int* __restrict__ indeg,
                            int* __restrict__ rowperm, int* __restrict__ sortpos,
                            int* __restrict__ chunk_off, int* __restrict__ chunk_max) {
  __shared__ int hist[64];
  __shared__ int base[64];
  int t = threadIdx.x;  // 256 threads
  if (t < 64) hist[t] = 0;
  __syncthreads();
  for (int r = t; r < NN; r += 256) {
    int d = indeg[r]; if (d > 63) d = 63;
    atomicAdd(&hist[d], 1);
  }
  __syncthreads();
  if (t == 0) {
    int acc = 0;
    for (int i = 0; i < 64; ++i) { base[i] = acc; acc += hist[i]; }
  }
  __syncthreads();
  for (int r = t; r < NN; r += 256) {
    int d = indeg[r]; if (d > 63) d = 63;
    int pos = atomicAdd(&base[d], 1);
    rowperm[pos] = r;
    sortpos[r] = pos;
  }
  __syncthreads();
  if (t < NCHUNK) {
    int m = 0;
    for (int i = 0; i < 64; ++i) {
      int d = indeg[rowperm[(t << 6) + i]];
      if (d > m) m = d;
    }
    chunk_max[t] = m;
  }
  __syncthreads();
  if (t == 0) {
    int acc = 0;
    for (int c = 0; c < NCHUNK; ++c) { chunk_off[c] = acc; acc += chunk_max[c] << 6; }
    chunk_off[NCHUNK] = acc;
  }
}

// zero only the used ELL region (+prefetch slack) of both buffers
__global__ void zero_ell(const int* __restrict__ chunk_off,
                         int2* __restrict__ e1, int2* __restrict__ e2) {
  int total = chunk_off[NCHUNK] + 256;
  int stride = gridDim.x * blockDim.x;
  for (int i = blockIdx.x * blockDim.x + threadIdx.x; i < total; i += stride) {
    e1[i] = make_int2(0, 0);
    e2[i] = make_int2(0, 0);
  }
}

// scatter edges into lane-major padded ELL: {swizzled byte offset, weight bits}
__global__ void fill_ell(const int* __restrict__ senders, const int* __restrict__ receivers,
                         const int* __restrict__ sortpos, const int* __restrict__ chunk_off,
                         const float* __restrict__ dinv, int* __restrict__ fillc,
                         int2* __restrict__ ell) {
  int e = blockIdx.x * blockDim.x + threadIdx.x;
  if (e < NE) {
    int r = receivers[e], s = senders[e];
    int p = sortpos[r];
    int tslot = atomicAdd(&fillc[r], 1);
    int slot = chunk_off[p >> 6] + (tslot << 6) + (p & 63);
    ell[slot] = make_int2(xbyte(s), __float_as_int(dinv[s]));
  }
}

// per-row counting sort of edge entries by rotated granule class (g - lane) & 7
// -> each slab's 64 lanes hit ~uniform granule positions (near-minimal conflicts)
__global__ void sort_ell(const int* __restrict__ chunk_off,
                         const int* __restrict__ chunk_max,
                         const int2* __restrict__ src, int2* __restrict__ dst) {
  int p = blockIdx.x * blockDim.x + threadIdx.x;  // 4096 threads = sorted row slots
  int c = p >> 6, l = p & 63;
  int base = chunk_off[c], maxd = chunk_max[c];
  if (maxd > 200) {  // safety: copy unsorted (never hit for random graphs)
    for (int t = 0; t < maxd; ++t) dst[base + (t << 6) + l] = src[base + (t << 6) + l];
    return;
  }
  unsigned long long cnt = 0;
  for (int t = 0; t < maxd; ++t) {
    int2 e = src[base + (t << 6) + l];
    int cl = (((e.x >> 4) & 7) - l) & 7;
    cnt += 1ull << (cl << 3);
  }
  unsigned long long pre = 0;  // packed exclusive prefix (bytes; total <= maxd < 256)
  for (int k = 1; k < 8; ++k) pre += cnt << (k << 3);
  unsigned long long used = 0;
  for (int t = 0; t < maxd; ++t) {
    int2 e = src[base + (t << 6) + l];
    int cl = (((e.x >> 4) & 7) - l) & 7;
    int pos = (int)(((pre + used) >> (cl << 3)) & 255);
    used += 1ull << (cl << 3);
    dst[base + (pos << 6) + l] = e;
  }
}

// ---- fused 16-step iteration: block owns cols [c0, c0+16) in LDS ----

__global__ __launch_bounds__(THREADS, 4)
void fused_kernel(const int2* __restrict__ ell,
                  const int* __restrict__ chunk_off,
                  const int* __restrict__ chunk_max,
                  const int* __restrict__ rowperm,
                  float* __restrict__ pe) {
  __shared__ __align__(16) h_t X[NN * CW];  // 128 KiB, swizzled
  char* Xb = (char*)X;
  int c0 = blockIdx.x * CW;
  int tid = threadIdx.x;
  int wave = tid >> 6, lane = tid & 63;

  // identity slice init
  for (int s = tid; s < NN; s += THREADS) {
    int d = s - c0;
    h8 lo, hi;
#pragma unroll
    for (int j = 0; j < 8; ++j) {
      lo[j] = (h_t)((d == j) ? 1.0f : 0.0f);
      hi[j] = (h_t)((d == 8 + j) ? 1.0f : 0.0f);
    }
    int xb = xbyte(s);
    *reinterpret_cast<h8*>(Xb + xb) = lo;
    *reinterpret_cast<h8*>(Xb + (xb ^ 16)) = hi;
  }
  __syncthreads();

  for (int k = 0; k < PED; ++k) {
    h8 rlo[PASSES], rhi[PASSES];
    int rxb[PASSES];
#pragma unroll
    for (int pass = 0; pass < PASSES; ++pass) {
      // boustrophedon: each wave's 4 chunk ranks sum to a constant -> balanced
      int chunk = (pass << 4) + ((pass & 1) ? (15 - wave) : wave);
      int base = chunk_off[chunk];
      int maxd = chunk_max[chunk];
      int r = rowperm[(chunk << 6) + lane];
      rxb[pass] = xbyte(r);
      float a[16];
#pragma unroll
      for (int j = 0; j < 16; ++j) a[j] = 0.f;
      const int2* ep = ell + base + lane;
      int2 cw = ep[0];   // padding entries (addr 0, w 0) make this always safe
      int2 n1 = ep[64];
      h8 lo = *reinterpret_cast<const h8*>(Xb + cw.x);
      h8 hi = *reinterpret_cast<const h8*>(Xb + (cw.x ^ 16));
      for (int t = 0; t < maxd; ++t) {
        int2 n2 = ep[128];     // 2-deep ELL prefetch (L2 latency)
        ep += 64;
        h8 nlo = *reinterpret_cast<const h8*>(Xb + n1.x);   // pipeline LDS gather
        h8 nhi = *reinterpret_cast<const h8*>(Xb + (n1.x ^ 16));
        float w = __int_as_float(cw.y);
#pragma unroll
        for (int j = 0; j < 8; ++j) {
          a[j]     = fmaf((float)lo[j], w, a[j]);
          a[8 + j] = fmaf((float)hi[j], w, a[8 + j]);
        }
        cw = n1; n1 = n2; lo = nlo; hi = nhi;
      }
      h8 plo, phi;
#pragma unroll
      for (int j = 0; j < 8; ++j) { plo[j] = (h_t)a[j]; phi[j] = (h_t)a[8 + j]; }
      rlo[pass] = plo; rhi[pass] = phi;
      int dj = r - c0;
      if (dj >= 0 && dj < CW) {            // rare: diagonal entry, fp32 pre-rounding
        float dv = a[0];
#pragma unroll
        for (int j = 1; j < 16; ++j) dv = (dj == j) ? a[j] : dv;
        pe[r * PED + k] = dv;
      }
    }
    __syncthreads();
#pragma unroll
    for (int pass = 0; pass < PASSES; ++pass) {
      int xb = rxb[pass];
      *reinterpret_cast<h8*>(Xb + xb) = rlo[pass];
      *reinterpret_cast<h8*>(Xb + (xb ^ 16)) = rhi[pass];
    }
    __syncthreads();
  }
}

// out[r,h] = sum_k pe[r,k] * W[k,h] + b[h]
__global__ void out_kernel(const float* __restrict__ pe, const float* __restrict__ W,
                           const float* __restrict__ bvec, float* __restrict__ out) {
  __shared__ float sW[PED * HID];
  int r = blockIdx.x;
  int h = threadIdx.x;
  for (int i = h; i < PED * HID; i += HID) sW[i] = W[i];
  __syncthreads();
  float acc = bvec[h];
  float p[PED];
#pragma unroll
  for (int kk = 0; kk < PED; ++kk) p[kk] = pe[r * PED + kk];
#pragma unroll
  for (int kk = 0; kk < PED; ++kk) acc = fmaf(p[kk], sW[kk * HID + h], acc);
  out[r * HID + h] = acc;
}

extern "C" void kernel_launch(void* const* d_in, const int* in_sizes, int n_in,
                              void* d_out, int out_size, void* d_ws, size_t ws_size,
                              hipStream_t stream) {
  // inputs: 0=nodes (unused), 1=senders, 2=receivers, 3=W, 4=b
  const int* senders = (const int*)d_in[1];
  const int* receivers = (const int*)d_in[2];
  const float* W = (const float*)d_in[3];
  const float* bvec = (const float*)d_in[4];
  float* out = (float*)d_out;

  char* p = (char*)d_ws;
  int* outdeg = (int*)p;    p += (size_t)NN * 4;
  int* indeg = (int*)p;     p += (size_t)NN * 4;
  int* fillc = (int*)p;     p += (size_t)NN * 4;
  float* dinv = (float*)p;  p += (size_t)NN * 4;
  int* rowperm = (int*)p;   p += (size_t)NN * 4;
  int* sortpos = (int*)p;   p += (size_t)NN * 4;
  int* chunk_off = (int*)p; p += 128 * 4;
  int* chunk_max = (int*)p; p += 128 * 4;
  float* pe = (float*)p;    p += (size_t)NN * PED * 4;
  size_t ell_slots = (size_t)64 * NE + 256;  // strict worst-case padded bound
  int2* ell = (int2*)p;     p += ell_slots * sizeof(int2);
  int2* ell2 = (int2*)p;

  hipMemsetAsync(d_ws, 0, (size_t)NN * 4 * 3, stream);  // outdeg/indeg/fillc
  count_kernel<<<NE / 256, 256, 0, stream>>>(senders, receivers, outdeg, indeg);
  deg_inv_kernel<<<NN / 256, 256, 0, stream>>>(outdeg, dinv);
  sort_kernel<<<1, 256, 0, stream>>>(indeg, rowperm, sortpos, chunk_off, chunk_max);
  zero_ell<<<256, 256, 0, stream>>>(chunk_off, ell, ell2);
  fill_ell<<<NE / 256, 256, 0, stream>>>(senders, receivers, sortpos, chunk_off, dinv, fillc, ell);
  sort_ell<<<NN / 256, 256, 0, stream>>>(chunk_off, chunk_max, ell, ell2);

  fused_kernel<<<NN / CW, THREADS, 0, stream>>>(ell2, chunk_off, chunk_max, rowperm, pe);

  out_kernel<<<NN, HID, 0, stream>>>(pe, W, bvec, out);
}

// Round 5
// 206.238 us; speedup vs baseline: 5.7117x; 1.0404x over previous
//
#include <hip/hip_runtime.h>

#define NN 4096
#define NE 32768
#define PED 16
#define HID 128
#define CW 16          // columns per block slice
#define NCHUNK 64      // NN/64 rows per chunk
#define THREADS 1024   // 16 waves
#define PASSES 4       // NCHUNK / 16 waves

typedef _Float16 h_t;
typedef _Float16 h8 __attribute__((ext_vector_type(8)));

// swizzled LDS BYTE offset of row s's low half (cols 0-7); high half = ^16.
// 128-B window of 4 rows; granule position g = f(s) spreads random rows
// across all 8 granule slots (hence all 32 banks).
__device__ __forceinline__ int xbyte(int s) {
  int g = ((s & 3) << 1) | ((s >> 2) & 1);
  return ((s >> 2) << 7) + (g << 4);
}

// ---- preprocessing (tiny, one-time) ----

__global__ void count_kernel(const int* __restrict__ senders,
                             const int* __restrict__ receivers,
                             int* __restrict__ outdeg, int* __restrict__ indeg) {
  int e = blockIdx.x * blockDim.x + threadIdx.x;
  if (e < NE) {
    atomicAdd(&outdeg[senders[e]], 1);
    atomicAdd(&indeg[receivers[e]], 1);
  }
}

// counting-sort rows by (clamped) in-degree; chunk max-degrees, ELL offsets, dinv
__global__ void sort_kernel(const int* __restrict__ indeg, const int* __restrict__ outdeg,
                            float* __restrict__ dinv,
                            int* __restrict__ rowperm, int* __restrict__ sortpos,
                            int* __restrict__ chunk_off, int* __restrict__ chunk_max) {
  __shared__ int hist[64];
  __shared__ int base[64];
  int t = threadIdx.x;  // 256 threads
  if (t < 64) hist[t] = 0;
  __syncthreads();
  for (int r = t; r < NN; r += 256) {
    int d = indeg[r]; if (d > 63) d = 63;
    atomicAdd(&hist[d], 1);
    int od = outdeg[r]; if (od < 1) od = 1;
    dinv[r] = 1.0f / (float)od;
  }
  __syncthreads();
  if (t == 0) {
    int acc = 0;
    for (int i = 0; i < 64; ++i) { base[i] = acc; acc += hist[i]; }
  }
  __syncthreads();
  for (int r = t; r < NN; r += 256) {
    int d = indeg[r]; if (d > 63) d = 63;
    int pos = atomicAdd(&base[d], 1);
    rowperm[pos] = r;
    sortpos[r] = pos;
  }
  __syncthreads();
  if (t < NCHUNK) {
    int m = 0;
    for (int i = 0; i < 64; ++i) {
      int d = indeg[rowperm[(t << 6) + i]];
      if (d > m) m = d;
    }
    chunk_max[t] = m;
  }
  __syncthreads();
  if (t == 0) {
    int acc = 0;
    for (int c = 0; c < NCHUNK; ++c) { chunk_off[c] = acc; acc += chunk_max[c] << 6; }
    chunk_off[NCHUNK] = acc;
  }
}

// zero the 256-entry prefetch tail of the scheduled ELL (src ELL needs no zeroing)
__global__ void zero_tail(const int* __restrict__ chunk_off, int2* __restrict__ e2) {
  int total = chunk_off[NCHUNK];
  e2[total + threadIdx.x] = make_int2(0, 0);
}

// scatter edges into lane-major ELL (fill order): {swizzled byte offset, weight bits}
__global__ void fill_ell(const int* __restrict__ senders, const int* __restrict__ receivers,
                         const int* __restrict__ sortpos, const int* __restrict__ chunk_off,
                         const float* __restrict__ dinv, int* __restrict__ fillc,
                         int2* __restrict__ ell) {
  int e = blockIdx.x * blockDim.x + threadIdx.x;
  if (e < NE) {
    int r = receivers[e], s = senders[e];
    int p = sortpos[r];
    int tslot = atomicAdd(&fillc[r], 1);
    int slot = chunk_off[p >> 6] + (tslot << 6) + (p & 63);
    ell[slot] = make_int2(xbyte(s), __float_as_int(dinv[s]));
  }
}

// schedule each lane's edges so slab t carries granule class (t+l)&7:
// rotated class cl=(g-l)&7 edges go to slots {cl, cl+8, cl+16, ...} (classes never
// collide mod 8); overflow edges fill leftover slots; padding entries get the
// slot's TARGET class in window 0 (w=0 -> broadcast-free, harmless).
__global__ void sched_ell(const int* __restrict__ chunk_off,
                          const int* __restrict__ chunk_max,
                          const int* __restrict__ rowperm,
                          const int* __restrict__ indeg,
                          const int2* __restrict__ src, int2* __restrict__ dst) {
  int p = blockIdx.x * blockDim.x + threadIdx.x;  // 4096 threads = sorted row slots
  int c = p >> 6, l = p & 63;
  int base = chunk_off[c], maxd = chunk_max[c];
  int d = indeg[rowperm[p]];
  if (maxd > 63) {  // safety fallback (never hit for Poisson(8) degrees)
    for (int t = 0; t < d; ++t) dst[base + (t << 6) + l] = src[base + (t << 6) + l];
    for (int t = d; t < maxd; ++t)
      dst[base + (t << 6) + l] = make_int2(((t + l) & 7) << 4, 0);
    return;
  }
  unsigned long long occ = 0;
  int placed[8] = {0, 0, 0, 0, 0, 0, 0, 0};
  // pass A: primaries
  for (int t = 0; t < d; ++t) {
    int2 e = src[base + (t << 6) + l];
    int cl = (((e.x >> 4) & 7) - l) & 7;
    int slot = cl + (placed[cl]++ << 3);
    if (slot < maxd) { dst[base + (slot << 6) + l] = e; occ |= 1ull << slot; }
  }
  // pass B: overflow edges -> lowest free slots (deterministic replay of A)
  int placed2[8] = {0, 0, 0, 0, 0, 0, 0, 0};
  for (int t = 0; t < d; ++t) {
    int2 e = src[base + (t << 6) + l];
    int cl = (((e.x >> 4) & 7) - l) & 7;
    int slot = cl + (placed2[cl]++ << 3);
    if (slot >= maxd) {
      int f = __builtin_ctzll(~occ & ((1ull << maxd) - 1));
      dst[base + (f << 6) + l] = e;
      occ |= 1ull << f;
    }
  }
  // pass C: padding with target-class dummy reads
  unsigned long long rem = ~occ & ((1ull << maxd) - 1);
  while (rem) {
    int slot = __builtin_ctzll(rem);
    rem &= rem - 1;
    dst[base + (slot << 6) + l] = make_int2(((slot + l) & 7) << 4, 0);
  }
}

// ---- fused 16-step iteration: block owns cols [c0, c0+16) in LDS ----

#define MIXL(acc, srcv) \
  asm("v_fma_mix_f32 %0, %1, %2, %0 op_sel_hi:[1,0,0]" : "+v"(acc) : "v"(srcv), "v"(w))
#define MIXH(acc, srcv) \
  asm("v_fma_mix_f32 %0, %1, %2, %0 op_sel:[1,0,0] op_sel_hi:[1,0,0]" : "+v"(acc) : "v"(srcv), "v"(w))

__global__ __launch_bounds__(THREADS, 4)
void fused_kernel(const int2* __restrict__ ell,
                  const int* __restrict__ chunk_off,
                  const int* __restrict__ chunk_max,
                  const int* __restrict__ rowperm,
                  float* __restrict__ pe) {
  __shared__ __align__(16) h_t X[NN * CW];  // 128 KiB, swizzled
  char* Xb = (char*)X;
  int c0 = blockIdx.x * CW;
  int tid = threadIdx.x;
  int wave = tid >> 6, lane = tid & 63;

  // identity slice init
  for (int s = tid; s < NN; s += THREADS) {
    int dd = s - c0;
    h8 lo8, hi8;
#pragma unroll
    for (int j = 0; j < 8; ++j) {
      lo8[j] = (h_t)((dd == j) ? 1.0f : 0.0f);
      hi8[j] = (h_t)((dd == 8 + j) ? 1.0f : 0.0f);
    }
    int xb = xbyte(s);
    *reinterpret_cast<h8*>(Xb + xb) = lo8;
    *reinterpret_cast<h8*>(Xb + (xb ^ 16)) = hi8;
  }
  __syncthreads();

  for (int k = 0; k < PED; ++k) {
    h8 rlo[PASSES], rhi[PASSES];
    int rxb[PASSES];
#pragma unroll
    for (int pass = 0; pass < PASSES; ++pass) {
      // boustrophedon: each wave's 4 chunk ranks sum to a constant -> balanced
      int chunk = (pass << 4) + ((pass & 1) ? (15 - wave) : wave);
      int base = chunk_off[chunk];
      int maxd = chunk_max[chunk];
      int r = rowperm[(chunk << 6) + lane];
      rxb[pass] = xbyte(r);
      float a[16];
#pragma unroll
      for (int j = 0; j < 16; ++j) a[j] = 0.f;
      const int2* ep = ell + base + lane;
      int2 e0 = ep[0];   // padding/slack entries are always safe to read & apply
      int2 e1 = ep[64];
      int2 e2 = ep[128];
      int4 lo = *reinterpret_cast<const int4*>(Xb + e0.x);
      int4 hi = *reinterpret_cast<const int4*>(Xb + (e0.x ^ 16));
      for (int t = 0; t < maxd; ++t) {
        int2 e3 = ep[192];   // 3-deep ELL prefetch (L2 latency)
        ep += 64;
        int4 nlo = *reinterpret_cast<const int4*>(Xb + e1.x);  // pipelined LDS gather
        int4 nhi = *reinterpret_cast<const int4*>(Xb + (e1.x ^ 16));
        float w = __int_as_float(e0.y);
        MIXL(a[0], lo.x);  MIXH(a[1], lo.x);
        MIXL(a[2], lo.y);  MIXH(a[3], lo.y);
        MIXL(a[4], lo.z);  MIXH(a[5], lo.z);
        MIXL(a[6], lo.w);  MIXH(a[7], lo.w);
        MIXL(a[8], hi.x);  MIXH(a[9], hi.x);
        MIXL(a[10], hi.y); MIXH(a[11], hi.y);
        MIXL(a[12], hi.z); MIXH(a[13], hi.z);
        MIXL(a[14], hi.w); MIXH(a[15], hi.w);
        e0 = e1; e1 = e2; e2 = e3; lo = nlo; hi = nhi;
      }
      h8 plo, phi;
#pragma unroll
      for (int j = 0; j < 8; ++j) { plo[j] = (h_t)a[j]; phi[j] = (h_t)a[8 + j]; }
      rlo[pass] = plo; rhi[pass] = phi;
      int dj = r - c0;
      if (dj >= 0 && dj < CW) {            // rare: diagonal entry, fp32 pre-rounding
        float dv = a[0];
#pragma unroll
        for (int j = 1; j < 16; ++j) dv = (dj == j) ? a[j] : dv;
        pe[r * PED + k] = dv;
      }
    }
    __syncthreads();
#pragma unroll
    for (int pass = 0; pass < PASSES; ++pass) {
      int xb = rxb[pass];
      *reinterpret_cast<h8*>(Xb + xb) = rlo[pass];
      *reinterpret_cast<h8*>(Xb + (xb ^ 16)) = rhi[pass];
    }
    __syncthreads();
  }
}

// out[r,h] = sum_k pe[r,k] * W[k,h] + b[h]
__global__ void out_kernel(const float* __restrict__ pe, const float* __restrict__ W,
                           const float* __restrict__ bvec, float* __restrict__ out) {
  __shared__ float sW[PED * HID];
  int r = blockIdx.x;
  int h = threadIdx.x;
  for (int i = h; i < PED * HID; i += HID) sW[i] = W[i];
  __syncthreads();
  float acc = bvec[h];
  float p[PED];
#pragma unroll
  for (int kk = 0; kk < PED; ++kk) p[kk] = pe[r * PED + kk];
#pragma unroll
  for (int kk = 0; kk < PED; ++kk) acc = fmaf(p[kk], sW[kk * HID + h], acc);
  out[r * HID + h] = acc;
}

extern "C" void kernel_launch(void* const* d_in, const int* in_sizes, int n_in,
                              void* d_out, int out_size, void* d_ws, size_t ws_size,
                              hipStream_t stream) {
  // inputs: 0=nodes (unused), 1=senders, 2=receivers, 3=W, 4=b
  const int* senders = (const int*)d_in[1];
  const int* receivers = (const int*)d_in[2];
  const float* W = (const float*)d_in[3];
  const float* bvec = (const float*)d_in[4];
  float* out = (float*)d_out;

  char* p = (char*)d_ws;
  int* outdeg = (int*)p;    p += (size_t)NN * 4;
  int* indeg = (int*)p;     p += (size_t)NN * 4;
  int* fillc = (int*)p;     p += (size_t)NN * 4;
  float* dinv = (float*)p;  p += (size_t)NN * 4;
  int* rowperm = (int*)p;   p += (size_t)NN * 4;
  int* sortpos = (int*)p;   p += (size_t)NN * 4;
  int* chunk_off = (int*)p; p += 128 * 4;
  int* chunk_max = (int*)p; p += 128 * 4;
  float* pe = (float*)p;    p += (size_t)NN * PED * 4;
  size_t ell_slots = (size_t)64 * NE + 256;  // strict worst-case padded bound
  int2* ell = (int2*)p;     p += ell_slots * sizeof(int2);
  int2* ell2 = (int2*)p;

  hipMemsetAsync(d_ws, 0, (size_t)NN * 4 * 3, stream);  // outdeg/indeg/fillc
  count_kernel<<<NE / 256, 256, 0, stream>>>(senders, receivers, outdeg, indeg);
  sort_kernel<<<1, 256, 0, stream>>>(indeg, outdeg, dinv, rowperm, sortpos, chunk_off, chunk_max);
  zero_tail<<<1, 256, 0, stream>>>(chunk_off, ell2);
  fill_ell<<<NE / 256, 256, 0, stream>>>(senders, receivers, sortpos, chunk_off, dinv, fillc, ell);
  sched_ell<<<NN / 256, 256, 0, stream>>>(chunk_off, chunk_max, rowperm, indeg, ell, ell2);

  fused_kernel<<<NN / CW, THREADS, 0, stream>>>(ell2, chunk_off, chunk_max, rowperm, pe);

  out_kernel<<<NN, HID, 0, stream>>>(pe, W, bvec, out);
}